// Round 7
// baseline (489.382 us; speedup 1.0000x reference)
//
#include <hip/hip_runtime.h>

// TBStars2 MoE sparse block — fp32 I/O, bf16 MFMA compute (m97-style GEMMs)
#define T 4096
#define Hdim 1024
#define Fdim 2048
#define NE 8
#define TOPK 2
#define TK (T*TOPK)

typedef unsigned short ushort_t;
typedef __attribute__((ext_vector_type(8))) short bf16x8;   // 8 x bf16 (4 VGPRs)
typedef __attribute__((ext_vector_type(4))) float floatx4;  // mfma accumulator

__device__ __forceinline__ ushort_t f2bf(float f) {
    unsigned u = __float_as_uint(f);
    u += 0x7fff + ((u >> 16) & 1);   // RNE
    return (ushort_t)(u >> 16);
}
__device__ __forceinline__ uint4 cvt8(const float4 a, const float4 b) {
    uint4 r;
    r.x = (unsigned)f2bf(a.x) | ((unsigned)f2bf(a.y) << 16);
    r.y = (unsigned)f2bf(a.z) | ((unsigned)f2bf(a.w) << 16);
    r.z = (unsigned)f2bf(b.x) | ((unsigned)f2bf(b.y) << 16);
    r.w = (unsigned)f2bf(b.z) | ((unsigned)f2bf(b.w) << 16);
    return r;
}
// async 16B global->LDS (per-lane gather src; LDS dest = wave base + lane*16)
__device__ __forceinline__ void gld16(const ushort_t* g, short* l) {
    __builtin_amdgcn_global_load_lds((const __attribute__((address_space(1))) void*)g,
                                     (__attribute__((address_space(3))) void*)l, 16, 0, 0);
}

// ---------------------------------------------------------------------------
// K0: merged fp32->bf16 convert for hs then w1. Exact grid, 8 elems/thread.
__global__ __launch_bounds__(256) void cvt2_kernel(
    const float* __restrict__ srcA, ushort_t* __restrict__ dstA, long n8A,
    const float* __restrict__ srcB, ushort_t* __restrict__ dstB)
{
    long i = (long)blockIdx.x * 256 + threadIdx.x;
    if (i < n8A) {
        float4 a = *(const float4*)(srcA + i * 8);
        float4 b = *(const float4*)(srcA + i * 8 + 4);
        *(uint4*)(dstA + i * 8) = cvt8(a, b);
    } else {
        long j = i - n8A;
        float4 a = *(const float4*)(srcB + j * 8);
        float4 b = *(const float4*)(srcB + j * 8 + 4);
        *(uint4*)(dstB + j * 8) = cvt8(a, b);
    }
}

// K0b: cvt w2 (n8 groups) AND zero the fp32 partial buffer (rest of grid).
__global__ __launch_bounds__(256) void cvtw2_zero_kernel(
    const float* __restrict__ src, ushort_t* __restrict__ dst, long n8,
    float* __restrict__ partial)
{
    long i = (long)blockIdx.x * 256 + threadIdx.x;
    if (i < n8) {
        float4 a = *(const float4*)(src + i * 8);
        float4 b = *(const float4*)(src + i * 8 + 4);
        *(uint4*)(dst + i * 8) = cvt8(a, b);
    } else {
        long j = i - n8;              // zero 8 floats per thread
        float4 z = make_float4(0.f, 0.f, 0.f, 0.f);
        *(float4*)(partial + j * 8)     = z;
        *(float4*)(partial + j * 8 + 4) = z;
    }
}

// ---------------------------------------------------------------------------
// K1: router. One wave per token, fp32. No atomics. Block 0 zeroes counts.
__global__ __launch_bounds__(64) void router_kernel(
    const float* __restrict__ hs, const float* __restrict__ gw,
    float* __restrict__ logits_out,
    int2* __restrict__ choice, float2* __restrict__ cwt, int* __restrict__ counts)
{
    const int t = blockIdx.x;
    const int lane = threadIdx.x;
    if (t == 0 && lane < NE) counts[lane] = 0;

    float hreg[16];
#pragma unroll
    for (int i = 0; i < 16; ++i)
        hreg[i] = hs[(long)t * Hdim + lane + 64 * i];

    float acc[NE];
#pragma unroll
    for (int e = 0; e < NE; ++e) {
        float s = 0.f;
#pragma unroll
        for (int i = 0; i < 16; ++i)
            s += hreg[i] * gw[e * Hdim + lane + 64 * i];
#pragma unroll
        for (int off = 32; off > 0; off >>= 1)
            s += __shfl_xor(s, off, 64);
        acc[e] = s;
    }

    if (lane < NE) logits_out[t * NE + lane] = acc[lane];

    if (lane == 0) {
        int i1 = 0;
#pragma unroll
        for (int e = 1; e < NE; ++e) if (acc[e] > acc[i1]) i1 = e;
        int i2 = -1;
#pragma unroll
        for (int e = 0; e < NE; ++e) {
            if (e == i1) continue;
            if (i2 < 0 || acc[e] > acc[i2]) i2 = e;
        }
        float p2 = __expf(acc[i2] - acc[i1]);
        float z  = 1.f + p2;
        choice[t] = make_int2(i1, i2);
        cwt[t]    = make_float2(1.f / z, p2 / z);
    }
}

// K1b: scatter. Block = 256 tokens. LDS histogram -> 8 global atomics/block.
__global__ __launch_bounds__(256) void scatter_kernel(
    const int2* __restrict__ choice, const float2* __restrict__ cwt,
    int* __restrict__ counts, int* __restrict__ tok_slot, float* __restrict__ tok_wt)
{
    __shared__ int lhist[NE];
    __shared__ int lbase[NE];
    __shared__ int lpos[NE];
    const int tid = threadIdx.x;
    if (tid < NE) { lhist[tid] = 0; lpos[tid] = 0; }
    __syncthreads();

    const int t = blockIdx.x * 256 + tid;
    int2   ch = choice[t];
    float2 wv = cwt[t];
    atomicAdd(&lhist[ch.x], 1);
    atomicAdd(&lhist[ch.y], 1);
    __syncthreads();

    if (tid < NE) lbase[tid] = atomicAdd(&counts[tid], lhist[tid]);
    __syncthreads();

    int p1 = atomicAdd(&lpos[ch.x], 1);   // ch.x != ch.y (top-2 distinct)
    int p2 = atomicAdd(&lpos[ch.y], 1);
    int o1 = lbase[ch.x] + p1;
    int o2 = lbase[ch.y] + p2;
    tok_slot[ch.x * T + o1] = t * TOPK + 0;
    tok_wt [ch.x * T + o1] = wv.x;
    tok_slot[ch.y * T + o2] = t * TOPK + 1;
    tok_wt [ch.y * T + o2] = wv.y;
}

// ---------------------------------------------------------------------------
// K2: gather-GEMM1 + SwiGLU. Tile: 128 rows x 64 f-cols (gate+up both staged).
// Launched as TWO f-half dispatches (f_base = 0, F/2) so each lands ~53 us —
// drops the top-5 visibility threshold below the other kernels.
__global__ __launch_bounds__(256) void gemm1_kernel(
    const ushort_t* __restrict__ hsb, const ushort_t* __restrict__ w1b,
    const int* __restrict__ counts, const int* __restrict__ tok_slot,
    ushort_t* __restrict__ actb, int f_base)
{
    const int e = blockIdx.z;
    const int cnt = counts[e];
    const int row0 = blockIdx.y * 128;
    if (row0 >= cnt) return;
    const int f0 = f_base + blockIdx.x * 64;

    __shared__ short As[128 * 32];    // 8 KB, row stride 32 elems (64 B)
    __shared__ short Bs[128 * 32];    // rows 0-63 gate, 64-127 up
    __shared__ int slotLds[128];

    const int tid = threadIdx.x;
    if (tid < 128) {
        int idx = row0 + tid;
        slotLds[tid] = (idx < cnt) ? tok_slot[e * T + idx] : -1;
    }
    __syncthreads();

    const int rA0 = tid >> 2,      rA1 = 64 + (tid >> 2);
    const int seg = (tid & 3) * 8;
    int s0 = slotLds[rA0], s1 = slotLds[rA1];
    const ushort_t* srcA0 = hsb + (long)((s0 >= 0 ? (s0 >> 1) : 0)) * Hdim + seg;
    const ushort_t* srcA1 = hsb + (long)((s1 >= 0 ? (s1 >> 1) : 0)) * Hdim + seg;
    const ushort_t* srcB0 = w1b + ((long)e * 2 * Fdim + (f0 + rA0)) * Hdim + seg;          // gate
    const ushort_t* srcB1 = w1b + ((long)e * 2 * Fdim + Fdim + (f0 + rA0)) * Hdim + seg;   // up

    const int lane = tid & 63;
    const int w = tid >> 6;
    const int wm = (w >> 1) * 64;
    const int wn = (w & 1) * 32;
    const int fr = lane & 15, fg = lane >> 4;

    floatx4 accg[4][2] = {};
    floatx4 accu[4][2] = {};

    for (int k0 = 0; k0 < Hdim; k0 += 32) {
        __syncthreads();
        gld16(srcA0 + k0, &As[tid * 8]);
        gld16(srcA1 + k0, &As[(256 + tid) * 8]);
        gld16(srcB0 + k0, &Bs[tid * 8]);
        gld16(srcB1 + k0, &Bs[(256 + tid) * 8]);
        __syncthreads();

        bf16x8 a[4], g[2], u[2];
#pragma unroll
        for (int ms = 0; ms < 4; ++ms)
            a[ms] = *(bf16x8*)&As[(wm + ms * 16 + fr) * 32 + fg * 8];
#pragma unroll
        for (int ns = 0; ns < 2; ++ns) {
            g[ns] = *(bf16x8*)&Bs[(wn + ns * 16 + fr) * 32 + fg * 8];
            u[ns] = *(bf16x8*)&Bs[(64 + wn + ns * 16 + fr) * 32 + fg * 8];
        }
#pragma unroll
        for (int ms = 0; ms < 4; ++ms)
#pragma unroll
            for (int ns = 0; ns < 2; ++ns) {
                accg[ms][ns] = __builtin_amdgcn_mfma_f32_16x16x32_bf16(a[ms], g[ns], accg[ms][ns], 0, 0, 0);
                accu[ms][ns] = __builtin_amdgcn_mfma_f32_16x16x32_bf16(a[ms], u[ns], accu[ms][ns], 0, 0, 0);
            }
    }

#pragma unroll
    for (int ms = 0; ms < 4; ++ms)
#pragma unroll
        for (int ns = 0; ns < 2; ++ns)
#pragma unroll
            for (int j = 0; j < 4; ++j) {
                int m = wm + ms * 16 + fg * 4 + j;
                int slot = slotLds[m];
                if (slot >= 0) {
                    int fcol = f0 + wn + ns * 16 + fr;
                    float gv = accg[ms][ns][j];
                    float uv = accu[ms][ns][j];
                    float av = (gv / (1.f + __expf(-gv))) * uv;
                    actb[(long)slot * Fdim + fcol] = f2bf(av);
                }
            }
}

// ---------------------------------------------------------------------------
// K3: gather-GEMM2, split-K x2. Each block: 128 rows x 128 h-cols, K=F/2=1024
// (32 steps — same proven loop shape as gemm1). Epilogue: atomicAdd into
// zeroed partial (R4 showed scattered fp32 atomics are ~free).
__global__ __launch_bounds__(256) void gemm2_kernel(
    const ushort_t* __restrict__ actb, const ushort_t* __restrict__ w2b,
    const int* __restrict__ counts, const int* __restrict__ tok_slot,
    const float* __restrict__ tok_wt, float* __restrict__ partial)
{
    const int e = blockIdx.z;
    const int cnt = counts[e];
    const int row0 = blockIdx.y * 128;
    if (row0 >= cnt) return;
    const int ks = blockIdx.x & 1;            // K-split half
    const int h0 = (blockIdx.x >> 1) * 128;
    const int kbase = ks * (Fdim / 2);

    __shared__ short As[128 * 32];
    __shared__ short Bs[128 * 32];
    __shared__ int   slotLds[128];
    __shared__ float wtLds[128];

    const int tid = threadIdx.x;
    if (tid < 128) {
        int idx = row0 + tid;
        bool ok = idx < cnt;
        slotLds[tid] = ok ? tok_slot[e * T + idx] : -1;
        wtLds[tid]   = ok ? tok_wt [e * T + idx] : 0.f;
    }
    __syncthreads();

    const int rA0 = tid >> 2, rA1 = 64 + (tid >> 2);
    const int seg = (tid & 3) * 8;
    int s0 = slotLds[rA0], s1 = slotLds[rA1];
    const ushort_t* srcA0 = actb + (long)(s0 >= 0 ? s0 : 0) * Fdim + kbase + seg;
    const ushort_t* srcA1 = actb + (long)(s1 >= 0 ? s1 : 0) * Fdim + kbase + seg;
    const ushort_t* srcB0 = w2b + ((long)e * Hdim + (h0 + rA0)) * Fdim + kbase + seg;
    const ushort_t* srcB1 = w2b + ((long)e * Hdim + (h0 + rA1)) * Fdim + kbase + seg;

    const int lane = tid & 63;
    const int w = tid >> 6;
    const int wm = (w >> 1) * 64;
    const int wn = (w & 1) * 64;
    const int fr = lane & 15, fg = lane >> 4;

    floatx4 acc[4][4] = {};

    for (int k0 = 0; k0 < Fdim / 2; k0 += 32) {
        __syncthreads();
        gld16(srcA0 + k0, &As[tid * 8]);
        gld16(srcA1 + k0, &As[(256 + tid) * 8]);
        gld16(srcB0 + k0, &Bs[tid * 8]);
        gld16(srcB1 + k0, &Bs[(256 + tid) * 8]);
        __syncthreads();

        bf16x8 a[4], b[4];
#pragma unroll
        for (int ms = 0; ms < 4; ++ms)
            a[ms] = *(bf16x8*)&As[(wm + ms * 16 + fr) * 32 + fg * 8];
#pragma unroll
        for (int ns = 0; ns < 4; ++ns)
            b[ns] = *(bf16x8*)&Bs[(wn + ns * 16 + fr) * 32 + fg * 8];
#pragma unroll
        for (int ms = 0; ms < 4; ++ms)
#pragma unroll
            for (int ns = 0; ns < 4; ++ns)
                acc[ms][ns] = __builtin_amdgcn_mfma_f32_16x16x32_bf16(a[ms], b[ns], acc[ms][ns], 0, 0, 0);
    }

#pragma unroll
    for (int ms = 0; ms < 4; ++ms)
#pragma unroll
        for (int ns = 0; ns < 4; ++ns)
#pragma unroll
            for (int j = 0; j < 4; ++j) {
                int m = wm + ms * 16 + fg * 4 + j;
                int slot = slotLds[m];
                if (slot >= 0) {
                    int hcol = h0 + wn + ns * 16 + fr;
                    atomicAdd(&partial[(long)slot * Hdim + hcol], acc[ms][ns][j] * wtLds[m]);
                }
            }
}

// ---------------------------------------------------------------------------
// K4: combine the two (token,k) partials -> fp32 final hidden states
__global__ __launch_bounds__(256) void combine_kernel(
    const float* __restrict__ partial, float* __restrict__ out)
{
    long i = (long)blockIdx.x * 256 + threadIdx.x;   // over T*H/4 float4 groups
    int t  = (int)(i / (Hdim / 4));
    int h4 = (int)(i % (Hdim / 4));
    const float4 p0 = *(const float4*)&partial[(long)(2 * t    ) * Hdim + h4 * 4];
    const float4 p1 = *(const float4*)&partial[(long)(2 * t + 1) * Hdim + h4 * 4];
    float4 s;
    s.x = p0.x + p1.x; s.y = p0.y + p1.y; s.z = p0.z + p1.z; s.w = p0.w + p1.w;
    *(float4*)&out[(long)t * Hdim + h4 * 4] = s;
}

// ---------------------------------------------------------------------------
extern "C" void kernel_launch(void* const* d_in, const int* in_sizes, int n_in,
                              void* d_out, int out_size, void* d_ws, size_t ws_size,
                              hipStream_t stream)
{
    const float* hs = (const float*)d_in[0];   // [T, H] fp32
    const float* gw = (const float*)d_in[1];   // [E, H] fp32
    const float* w1 = (const float*)d_in[2];   // [E, 2F, H] fp32
    const float* w2 = (const float*)d_in[3];   // [E, H, F] fp32

    float* out        = (float*)d_out;          // [T*H] final hidden (fp32)
    float* logits_out = out + (long)T * Hdim;   // [T*E] router logits (fp32)

    // workspace layout (~104.3 MB):
    // w1region recycled after gemm1: lower 32 MB = w2b, upper 32 MB = partial.
    // choice/cwt alias the first 64 KB of actb (dead before gemm1 writes it).
    char* ws = (char*)d_ws;
    size_t off = 0;
    int* counts = (int*)(ws + off);          off += 256;
    int* tok_slot = (int*)(ws + off);        off += (size_t)NE * T * sizeof(int);
    float* tok_wt = (float*)(ws + off);      off += (size_t)NE * T * sizeof(float);
    off = (off + 255) & ~(size_t)255;
    ushort_t* hsb = (ushort_t*)(ws + off);   off += (size_t)T * Hdim * sizeof(ushort_t);   // 8 MB
    off = (off + 255) & ~(size_t)255;
    char* w1region = ws + off;               off += (size_t)NE * 2 * Fdim * Hdim * sizeof(ushort_t); // 64 MB
    ushort_t* w1b = (ushort_t*)w1region;
    ushort_t* w2b = (ushort_t*)w1region;                                     // 32 MB (lower half)
    float* partial = (float*)(w1region + (size_t)NE * Hdim * Fdim * sizeof(ushort_t)); // 32 MB (upper half)
    off = (off + 255) & ~(size_t)255;
    ushort_t* actb = (ushort_t*)(ws + off);  off += (size_t)TK * Fdim * sizeof(ushort_t);  // 32 MB
    int2*   choice = (int2*)actb;                       // 32 KB  (dead before gemm1)
    float2* cwt    = (float2*)((char*)actb + (size_t)T * sizeof(int2));   // 32 KB

    const long n8_hs = (long)T * Hdim / 8;                    //   524288
    const long n8_w1 = (long)NE * 2 * Fdim * Hdim / 8;        //  4194304
    const long n8_w2 = (long)NE * Hdim * Fdim / 8;            //  2097152
    const long n8_pz = (long)TK * Hdim / 8;                   //  1048576 (partial zero)

    cvt2_kernel<<<(int)((n8_hs + n8_w1) / 256), 256, 0, stream>>>(hs, hsb, n8_hs, w1, w1b);
    router_kernel<<<T, 64, 0, stream>>>(hs, gw, logits_out, choice, cwt, counts);
    scatter_kernel<<<T / 256, 256, 0, stream>>>(choice, cwt, counts, tok_slot, tok_wt);
    gemm1_kernel<<<dim3(Fdim / 128, T / 128, NE), 256, 0, stream>>>(hsb, w1b, counts, tok_slot, actb, 0);
    gemm1_kernel<<<dim3(Fdim / 128, T / 128, NE), 256, 0, stream>>>(hsb, w1b, counts, tok_slot, actb, Fdim / 2);
    cvtw2_zero_kernel<<<(int)((n8_w2 + n8_pz) / 256), 256, 0, stream>>>(w2, w2b, n8_w2, partial);
    gemm2_kernel<<<dim3((Hdim / 128) * 2, T / 128, NE), 256, 0, stream>>>(actb, w2b, counts, tok_slot, tok_wt, partial);
    combine_kernel<<<(int)((long)T * Hdim / 4 / 256), 256, 0, stream>>>(partial, out);
}

// Round 8
// 433.626 us; speedup vs baseline: 1.1286x; 1.1286x over previous
//
#include <hip/hip_runtime.h>

// TBStars2 MoE sparse block — fp32 I/O, bf16 MFMA compute
// R8: BK=64 K-loops (half the barrier drains), XOR-swizzled LDS (bank-balanced
// ds_read_b128), gemm2 reverted to R6 form, hs-cvt fused into router.
#define T 4096
#define Hdim 1024
#define Fdim 2048
#define NE 8
#define TOPK 2
#define TK (T*TOPK)

typedef unsigned short ushort_t;
typedef __attribute__((ext_vector_type(8))) short bf16x8;   // 8 x bf16 (4 VGPRs)
typedef __attribute__((ext_vector_type(4))) float floatx4;  // mfma accumulator

__device__ __forceinline__ ushort_t f2bf(float f) {
    unsigned u = __float_as_uint(f);
    u += 0x7fff + ((u >> 16) & 1);   // RNE
    return (ushort_t)(u >> 16);
}
__device__ __forceinline__ uint4 cvt8(const float4 a, const float4 b) {
    uint4 r;
    r.x = (unsigned)f2bf(a.x) | ((unsigned)f2bf(a.y) << 16);
    r.y = (unsigned)f2bf(a.z) | ((unsigned)f2bf(a.w) << 16);
    r.z = (unsigned)f2bf(b.x) | ((unsigned)f2bf(b.y) << 16);
    r.w = (unsigned)f2bf(b.z) | ((unsigned)f2bf(b.w) << 16);
    return r;
}
// async 16B global->LDS (per-lane gather src; LDS dest = wave base + lane*16)
__device__ __forceinline__ void gld16(const ushort_t* g, short* l) {
    __builtin_amdgcn_global_load_lds((const __attribute__((address_space(1))) void*)g,
                                     (__attribute__((address_space(3))) void*)l, 16, 0, 0);
}

// ---------------------------------------------------------------------------
// K0: fp32 -> bf16 convert, exact grid, 8 elems/thread
__global__ __launch_bounds__(256) void cvt_kernel(const float* __restrict__ src,
                                                  ushort_t* __restrict__ dst)
{
    long i = (long)blockIdx.x * 256 + threadIdx.x;
    float4 a = *(const float4*)(src + i * 8);
    float4 b = *(const float4*)(src + i * 8 + 4);
    *(uint4*)(dst + i * 8) = cvt8(a, b);
}

// ---------------------------------------------------------------------------
// K1: router. One wave per token, fp32. Also converts its hs row -> hsb (bf16)
// and (block 0) zeroes counts.
__global__ __launch_bounds__(64) void router_kernel(
    const float* __restrict__ hs, const float* __restrict__ gw,
    float* __restrict__ logits_out, ushort_t* __restrict__ hsb,
    int2* __restrict__ choice, float2* __restrict__ cwt, int* __restrict__ counts)
{
    const int t = blockIdx.x;
    const int lane = threadIdx.x;
    if (t == 0 && lane < NE) counts[lane] = 0;

    float hreg[16];
#pragma unroll
    for (int i = 0; i < 16; ++i)
        hreg[i] = hs[(long)t * Hdim + lane + 64 * i];

#pragma unroll
    for (int i = 0; i < 16; ++i)
        hsb[(long)t * Hdim + lane + 64 * i] = f2bf(hreg[i]);

    float acc[NE];
#pragma unroll
    for (int e = 0; e < NE; ++e) {
        float s = 0.f;
#pragma unroll
        for (int i = 0; i < 16; ++i)
            s += hreg[i] * gw[e * Hdim + lane + 64 * i];
#pragma unroll
        for (int off = 32; off > 0; off >>= 1)
            s += __shfl_xor(s, off, 64);
        acc[e] = s;
    }

    if (lane < NE) logits_out[t * NE + lane] = acc[lane];

    if (lane == 0) {
        int i1 = 0;
#pragma unroll
        for (int e = 1; e < NE; ++e) if (acc[e] > acc[i1]) i1 = e;
        int i2 = -1;
#pragma unroll
        for (int e = 0; e < NE; ++e) {
            if (e == i1) continue;
            if (i2 < 0 || acc[e] > acc[i2]) i2 = e;
        }
        float p2 = __expf(acc[i2] - acc[i1]);
        float z  = 1.f + p2;
        choice[t] = make_int2(i1, i2);
        cwt[t]    = make_float2(1.f / z, p2 / z);
    }
}

// K1b: scatter. Block = 256 tokens. LDS histogram -> 8 global atomics/block.
__global__ __launch_bounds__(256) void scatter_kernel(
    const int2* __restrict__ choice, const float2* __restrict__ cwt,
    int* __restrict__ counts, int* __restrict__ tok_slot, float* __restrict__ tok_wt)
{
    __shared__ int lhist[NE];
    __shared__ int lbase[NE];
    __shared__ int lpos[NE];
    const int tid = threadIdx.x;
    if (tid < NE) { lhist[tid] = 0; lpos[tid] = 0; }
    __syncthreads();

    const int t = blockIdx.x * 256 + tid;
    int2   ch = choice[t];
    float2 wv = cwt[t];
    atomicAdd(&lhist[ch.x], 1);
    atomicAdd(&lhist[ch.y], 1);
    __syncthreads();

    if (tid < NE) lbase[tid] = atomicAdd(&counts[tid], lhist[tid]);
    __syncthreads();

    int p1 = atomicAdd(&lpos[ch.x], 1);   // ch.x != ch.y
    int p2 = atomicAdd(&lpos[ch.y], 1);
    int o1 = lbase[ch.x] + p1;
    int o2 = lbase[ch.y] + p2;
    tok_slot[ch.x * T + o1] = t * TOPK + 0;
    tok_wt [ch.x * T + o1] = wv.x;
    tok_slot[ch.y * T + o2] = t * TOPK + 1;
    tok_wt [ch.y * T + o2] = wv.y;
}

// ---------------------------------------------------------------------------
// K2: gather-GEMM1 + SwiGLU. 128 slots x 64 f (gate+up). BK=64, 16 K-steps.
// LDS rows are 64 elems (128 B); chunk c of row r stores global chunk c^(r&7)
// so ds_read_b128 is bank-balanced (8 touches/bank = minimum).
__global__ __launch_bounds__(256) void gemm1_kernel(
    const ushort_t* __restrict__ hsb, const ushort_t* __restrict__ w1b,
    const int* __restrict__ counts, const int* __restrict__ tok_slot,
    ushort_t* __restrict__ actb)
{
    const int e = blockIdx.z;
    const int cnt = counts[e];
    const int row0 = blockIdx.y * 128;
    if (row0 >= cnt) return;
    const int f0 = blockIdx.x * 64;

    __shared__ short As[128 * 64];    // 16 KB
    __shared__ short Bs[128 * 64];    // 16 KB: rows 0-63 gate, 64-127 up
    __shared__ int slotLds[128];

    const int tid = threadIdx.x;
    if (tid < 128) {
        int idx = row0 + tid;
        slotLds[tid] = (idx < cnt) ? tok_slot[e * T + idx] : -1;
    }
    __syncthreads();

    // staging pointers: 4 A-chunks + 4 B-chunks per thread (1024 chunks each)
    const ushort_t* srcA[4];
    const ushort_t* srcB[4];
#pragma unroll
    for (int i = 0; i < 4; ++i) {
        int ci = i * 256 + tid;            // 0..1023
        int r  = ci >> 3;                  // LDS row 0..127
        int gc = (ci & 7) ^ (r & 7);       // swizzled global chunk
        int s  = slotLds[r];
        srcA[i] = hsb + (long)(s >= 0 ? (s >> 1) : 0) * Hdim + gc * 8;
        long frow = (r < 64) ? (long)(f0 + r) : (long)(Fdim + f0 + (r - 64));
        srcB[i] = w1b + ((long)e * 2 * Fdim + frow) * Hdim + gc * 8;
    }

    const int lane = tid & 63;
    const int w = tid >> 6;
    const int wm = (w >> 1) * 64;
    const int wn = (w & 1) * 32;
    const int fr = lane & 15, fg = lane >> 4;
    const int cs0 = (fg ^ (fr & 7)) * 8;          // kk=0 chunk byte-swz (elems)
    const int cs1 = ((4 + fg) ^ (fr & 7)) * 8;    // kk=1

    floatx4 accg[4][2] = {};
    floatx4 accu[4][2] = {};

    for (int k0 = 0; k0 < Hdim; k0 += 64) {
        __syncthreads();
#pragma unroll
        for (int i = 0; i < 4; ++i) gld16(srcA[i] + k0, &As[(i * 256 + tid) * 8]);
#pragma unroll
        for (int i = 0; i < 4; ++i) gld16(srcB[i] + k0, &Bs[(i * 256 + tid) * 8]);
        __syncthreads();

#pragma unroll
        for (int kk = 0; kk < 2; ++kk) {
            const int cs = kk ? cs1 : cs0;
            bf16x8 a[4], g[2], u[2];
#pragma unroll
            for (int ms = 0; ms < 4; ++ms)
                a[ms] = *(bf16x8*)&As[(wm + ms * 16 + fr) * 64 + cs];
#pragma unroll
            for (int ns = 0; ns < 2; ++ns) {
                g[ns] = *(bf16x8*)&Bs[(wn + ns * 16 + fr) * 64 + cs];
                u[ns] = *(bf16x8*)&Bs[(64 + wn + ns * 16 + fr) * 64 + cs];
            }
#pragma unroll
            for (int ms = 0; ms < 4; ++ms)
#pragma unroll
                for (int ns = 0; ns < 2; ++ns) {
                    accg[ms][ns] = __builtin_amdgcn_mfma_f32_16x16x32_bf16(a[ms], g[ns], accg[ms][ns], 0, 0, 0);
                    accu[ms][ns] = __builtin_amdgcn_mfma_f32_16x16x32_bf16(a[ms], u[ns], accu[ms][ns], 0, 0, 0);
                }
        }
    }

#pragma unroll
    for (int ms = 0; ms < 4; ++ms)
#pragma unroll
        for (int ns = 0; ns < 2; ++ns)
#pragma unroll
            for (int j = 0; j < 4; ++j) {
                int m = wm + ms * 16 + fg * 4 + j;
                int slot = slotLds[m];
                if (slot >= 0) {
                    int fcol = f0 + wn + ns * 16 + fr;
                    float gv = accg[ms][ns][j];
                    float uv = accu[ms][ns][j];
                    float av = (gv / (1.f + __expf(-gv))) * uv;
                    actb[(long)slot * Fdim + fcol] = f2bf(av);
                }
            }
}

// ---------------------------------------------------------------------------
// K3: gather-GEMM2, 128x128 tile, 512 threads (8 waves, 2x4), BK=64, 32 steps,
// plain stores: partial[slot, h] = wt * (act @ w2^T).
__global__ __launch_bounds__(512) void gemm2_kernel(
    const ushort_t* __restrict__ actb, const ushort_t* __restrict__ w2b,
    const int* __restrict__ counts, const int* __restrict__ tok_slot,
    const float* __restrict__ tok_wt, float* __restrict__ partial)
{
    const int e = blockIdx.z;
    const int cnt = counts[e];
    const int row0 = blockIdx.y * 128;
    if (row0 >= cnt) return;
    const int h0 = blockIdx.x * 128;

    __shared__ short As[128 * 64];
    __shared__ short Bs[128 * 64];
    __shared__ int   slotLds[128];
    __shared__ float wtLds[128];

    const int tid = threadIdx.x;
    if (tid < 128) {
        int idx = row0 + tid;
        bool ok = idx < cnt;
        slotLds[tid] = ok ? tok_slot[e * T + idx] : -1;
        wtLds[tid]   = ok ? tok_wt [e * T + idx] : 0.f;
    }
    __syncthreads();

    const ushort_t* srcA[2];
    const ushort_t* srcB[2];
#pragma unroll
    for (int i = 0; i < 2; ++i) {
        int ci = i * 512 + tid;            // 0..1023
        int r  = ci >> 3;
        int gc = (ci & 7) ^ (r & 7);
        int s  = slotLds[r];
        srcA[i] = actb + (long)(s >= 0 ? s : 0) * Fdim + gc * 8;
        srcB[i] = w2b + ((long)e * Hdim + (h0 + r)) * Fdim + gc * 8;
    }

    const int lane = tid & 63;
    const int w = tid >> 6;              // 0..7
    const int wm = (w >> 2) * 64;
    const int wn = (w & 3) * 32;
    const int fr = lane & 15, fg = lane >> 4;
    const int cs0 = (fg ^ (fr & 7)) * 8;
    const int cs1 = ((4 + fg) ^ (fr & 7)) * 8;

    floatx4 acc[4][2] = {};

    for (int k0 = 0; k0 < Fdim; k0 += 64) {
        __syncthreads();
        gld16(srcA[0] + k0, &As[tid * 8]);
        gld16(srcA[1] + k0, &As[(512 + tid) * 8]);
        gld16(srcB[0] + k0, &Bs[tid * 8]);
        gld16(srcB[1] + k0, &Bs[(512 + tid) * 8]);
        __syncthreads();

#pragma unroll
        for (int kk = 0; kk < 2; ++kk) {
            const int cs = kk ? cs1 : cs0;
            bf16x8 a[4], b[2];
#pragma unroll
            for (int ms = 0; ms < 4; ++ms)
                a[ms] = *(bf16x8*)&As[(wm + ms * 16 + fr) * 64 + cs];
#pragma unroll
            for (int ns = 0; ns < 2; ++ns)
                b[ns] = *(bf16x8*)&Bs[(wn + ns * 16 + fr) * 64 + cs];
#pragma unroll
            for (int ms = 0; ms < 4; ++ms)
#pragma unroll
                for (int ns = 0; ns < 2; ++ns)
                    acc[ms][ns] = __builtin_amdgcn_mfma_f32_16x16x32_bf16(a[ms], b[ns], acc[ms][ns], 0, 0, 0);
        }
    }

#pragma unroll
    for (int ms = 0; ms < 4; ++ms)
#pragma unroll
        for (int ns = 0; ns < 2; ++ns)
#pragma unroll
            for (int j = 0; j < 4; ++j) {
                int m = wm + ms * 16 + fg * 4 + j;
                int slot = slotLds[m];
                if (slot >= 0) {
                    int hcol = h0 + wn + ns * 16 + fr;
                    partial[(long)slot * Hdim + hcol] = acc[ms][ns][j] * wtLds[m];
                }
            }
}

// ---------------------------------------------------------------------------
// K4: combine the two (token,k) partials -> fp32 final hidden states
__global__ __launch_bounds__(256) void combine_kernel(
    const float* __restrict__ partial, float* __restrict__ out)
{
    long i = (long)blockIdx.x * 256 + threadIdx.x;   // over T*H/4 float4 groups
    int t  = (int)(i / (Hdim / 4));
    int h4 = (int)(i % (Hdim / 4));
    const float4 p0 = *(const float4*)&partial[(long)(2 * t    ) * Hdim + h4 * 4];
    const float4 p1 = *(const float4*)&partial[(long)(2 * t + 1) * Hdim + h4 * 4];
    float4 s;
    s.x = p0.x + p1.x; s.y = p0.y + p1.y; s.z = p0.z + p1.z; s.w = p0.w + p1.w;
    *(float4*)&out[(long)t * Hdim + h4 * 4] = s;
}

// ---------------------------------------------------------------------------
extern "C" void kernel_launch(void* const* d_in, const int* in_sizes, int n_in,
                              void* d_out, int out_size, void* d_ws, size_t ws_size,
                              hipStream_t stream)
{
    const float* hs = (const float*)d_in[0];   // [T, H] fp32
    const float* gw = (const float*)d_in[1];   // [E, H] fp32
    const float* w1 = (const float*)d_in[2];   // [E, 2F, H] fp32
    const float* w2 = (const float*)d_in[3];   // [E, H, F] fp32

    float* out        = (float*)d_out;          // [T*H] final hidden (fp32)
    float* logits_out = out + (long)T * Hdim;   // [T*E] router logits (fp32)

    // workspace (~104.3 MB): w1region recycled after gemm1 (lower 32 MB = w2b,
    // upper 32 MB = partial). choice/cwt alias actb's head (dead before gemm1).
    char* ws = (char*)d_ws;
    size_t off = 0;
    int* counts = (int*)(ws + off);          off += 256;
    int* tok_slot = (int*)(ws + off);        off += (size_t)NE * T * sizeof(int);
    float* tok_wt = (float*)(ws + off);      off += (size_t)NE * T * sizeof(float);
    off = (off + 255) & ~(size_t)255;
    ushort_t* hsb = (ushort_t*)(ws + off);   off += (size_t)T * Hdim * sizeof(ushort_t);   // 8 MB
    off = (off + 255) & ~(size_t)255;
    char* w1region = ws + off;               off += (size_t)NE * 2 * Fdim * Hdim * sizeof(ushort_t); // 64 MB
    ushort_t* w1b = (ushort_t*)w1region;
    ushort_t* w2b = (ushort_t*)w1region;                                     // 32 MB (lower half)
    float* partial = (float*)(w1region + (size_t)NE * Hdim * Fdim * sizeof(ushort_t)); // 32 MB (upper half)
    off = (off + 255) & ~(size_t)255;
    ushort_t* actb = (ushort_t*)(ws + off);  off += (size_t)TK * Fdim * sizeof(ushort_t);  // 32 MB
    int2*   choice = (int2*)actb;                       // 32 KB  (dead before gemm1)
    float2* cwt    = (float2*)((char*)actb + (size_t)T * sizeof(int2));   // 32 KB

    const long n8_w1 = (long)NE * 2 * Fdim * Hdim / 8;        //  4194304
    const long n8_w2 = (long)NE * Hdim * Fdim / 8;            //  2097152

    cvt_kernel<<<(int)(n8_w1 / 256), 256, 0, stream>>>(w1, w1b);
    router_kernel<<<T, 64, 0, stream>>>(hs, gw, logits_out, hsb, choice, cwt, counts);
    scatter_kernel<<<T / 256, 256, 0, stream>>>(choice, cwt, counts, tok_slot, tok_wt);
    gemm1_kernel<<<dim3(Fdim / 64, T / 128, NE), 256, 0, stream>>>(hsb, w1b, counts, tok_slot, actb);
    cvt_kernel<<<(int)(n8_w2 / 256), 256, 0, stream>>>(w2, w2b);   // into recycled w1b (lower half)
    gemm2_kernel<<<dim3(Hdim / 128, T / 128, NE), 512, 0, stream>>>(actb, w2b, counts, tok_slot, tok_wt, partial);
    combine_kernel<<<(int)((long)T * Hdim / 4 / 256), 256, 0, stream>>>(partial, out);
}